// Round 9
// baseline (160.072 us; speedup 1.0000x reference)
//
#include <hip/hip_runtime.h>
#include <hip/hip_bf16.h>
#include <math.h>

// Problem constants (fixed by setup_inputs)
#define B_    16
#define C_    256
#define P_    16384          // 128*128
#define K_    101            // num_class + 1
#define S_    17             // B + 1 slots per class
#define V_    1717           // K_ * S_
#define GN_   1792           // V_ padded to 28*64
#define NPQ_  8              // pixel-slice partials (2048 px per slice)
#define LPITCH 260           // LDS row pitch in dwords (16B-aligned, bank-friendly)
#define TEMP_ 0.07f
#define INV_SQRT_T 3.7796447300922720f   // 1/sqrt(0.07)

typedef __bf16 bf16x8 __attribute__((ext_vector_type(8)));
typedef float f32x4 __attribute__((ext_vector_type(4)));
typedef int   i32x4 __attribute__((ext_vector_type(4)));

__device__ __forceinline__ void atomAddGlb(float* p, float v) {
  __hip_atomic_fetch_add(p, v, __ATOMIC_RELAXED, __HIP_MEMORY_SCOPE_AGENT);
}

// pack fp32 x into one dword: low16 = bf16(hi), high16 = bf16(x - hi). Exact.
__device__ __forceinline__ unsigned packHiLo(float x) {
  const unsigned u = __float_as_uint(x);
  const unsigned h = u & 0xFFFF0000u;
  const unsigned l = __float_as_uint(x - __uint_as_float(h));
  return __builtin_amdgcn_perm(l, u, 0x07060302u);  // [l3,l2,u3,u2]
}

// ---------------------------------------------------------------------------
// K1: segmented sums via MFMA, CONTIGUOUS global loads through LDS.
// R8 evidence: scattered 16x64B-per-instruction feature reads cap at ~2.7TB/s
// (HBM row-buffer thrash); poison-fill (contiguous) hits 6.9TB/s.  Now each
// global load is 1KB from ONE feature row.  Per block: (b, 32-ch group cg,
// 2048-px group pqg), 8 chunks of 256px; per chunk each wave stages 8 rows
// (pack hi|lo bf16 in regs -> ds_write_b128), then computes 4 of 16 windows.
// k-slot<->pixel map, A-build, MFMA identical to the absmax-0.0 R8 kernel.
// Grid: 1024 working blocks @ (256,4) -> 4 blocks/CU; +16 histogram blocks.
// ---------------------------------------------------------------------------
__global__ __launch_bounds__(256, 4) void k_segsum(
    const int* __restrict__ labels, const float* __restrict__ feats,
    float* __restrict__ psum, unsigned* __restrict__ counts) {
  __shared__ unsigned s_pk[32 * LPITCH];
  __shared__ unsigned s_cnt[102];
  const int id = blockIdx.x;
  const int tid = threadIdx.x;

  if (id >= 1024) {  // ---- label counts for batch id-1024 ----
    const int b = id - 1024;
    if (tid < 102) s_cnt[tid] = 0u;
    __syncthreads();
    for (int i = 0; i < 64; ++i) {
      int lab = labels[b * P_ + i * 256 + tid];
      if ((unsigned)lab > 100u) lab = 101;
      atomicAdd(&s_cnt[lab], 1u);
    }
    __syncthreads();
    if (tid < K_) counts[b * K_ + tid] = s_cnt[tid];
    return;
  }

  // cg innermost so the 8 blocks sharing (b,pqg) labels are dispatch-adjacent
  const int cg = id & 7, pqg = (id >> 3) & 7, b = id >> 6;
  const int wv = tid >> 6, ln = tid & 63;
  const int lg = ln >> 4;    // lane group 0..3
  const int lc = ln & 15;    // A row (class) / B col (channel)
  const int pbase = pqg * 2048;
  const float* fbl = feats + ((size_t)b * C_ + cg * 32) * P_ + pbase;
  const int* lbl = labels + b * P_ + pbase;

  f32x4 acc[2][7];
#pragma unroll
  for (int ct = 0; ct < 2; ++ct)
#pragma unroll
    for (int t = 0; t < 7; ++t) acc[ct][t] = (f32x4)0.f;

  for (int ck = 0; ck < 8; ++ck) {
    const int cb = ck * 256;
    __syncthreads();  // previous chunk's readers done before overwrite
    // ---- stage: 8 rows per wave, 1KB contiguous per load instruction ----
#pragma unroll
    for (int rr = 0; rr < 8; ++rr) {
      const int row = wv * 8 + rr;
      const float4 f = *(const float4*)&fbl[(size_t)row * P_ + cb + ln * 4];
      i32x4 pk;
      pk[0] = (int)packHiLo(f.x); pk[1] = (int)packHiLo(f.y);
      pk[2] = (int)packHiLo(f.z); pk[3] = (int)packHiLo(f.w);
      *(i32x4*)&s_pk[row * LPITCH + ln * 4] = pk;
    }
    __syncthreads();
    // ---- compute: 4 windows of 16px per wave ----
#pragma unroll
    for (int wi = 0; wi < 4; ++wi) {
      const int win = wv * 4 + wi;
      const i32x4 lv = *(const i32x4*)&lbl[cb + win * 16 + lg * 4];
      int d[4];
#pragma unroll
      for (int r = 0; r < 4; ++r) d[r] = lv[r] - lc;
      const bf16x8 b0 = __builtin_bit_cast(
          bf16x8, *(const i32x4*)&s_pk[lc * LPITCH + win * 16 + lg * 4]);
      const bf16x8 b1 = __builtin_bit_cast(
          bf16x8, *(const i32x4*)&s_pk[(16 + lc) * LPITCH + win * 16 + lg * 4]);
#pragma unroll
      for (int t = 0; t < 7; ++t) {
        const int m0 = t * 16;
        i32x4 av;
#pragma unroll
        for (int r = 0; r < 4; ++r)
          av[r] = (d[r] == m0) ? (int)0x3F803F80 : 0;
        const bf16x8 a = __builtin_bit_cast(bf16x8, av);
        acc[0][t] = __builtin_amdgcn_mfma_f32_16x16x32_bf16(a, b0, acc[0][t], 0, 0, 0);
        acc[1][t] = __builtin_amdgcn_mfma_f32_16x16x32_bf16(a, b1, acc[1][t], 0, 0, 0);
      }
    }
  }
  // ---- block reduce over 4 waves (LDS reused); waves 0/1 write psum ----
  __syncthreads();
  f32x4(*s_red)[256] = (f32x4(*)[256])s_pk;
  float* pbas = psum + ((size_t)(pqg * 16 + b) * K_) * 256 + cg * 32;
#pragma unroll
  for (int t = 0; t < 7; ++t) {
    s_red[0][wv * 64 + ln] = acc[0][t];
    s_red[1][wv * 64 + ln] = acc[1][t];
    __syncthreads();
    if (wv < 2) {
      const f32x4 a0 = s_red[wv][ln], a1 = s_red[wv][64 + ln];
      const f32x4 a2 = s_red[wv][128 + ln], a3 = s_red[wv][192 + ln];
#pragma unroll
      for (int r = 0; r < 4; ++r) {
        const int row = t * 16 + lg * 4 + r;
        if (row < K_)
          pbas[(size_t)row * 256 + wv * 16 + lc] =
              a0[r] + a1[r] + a2[r] + a3[r];
      }
    }
    __syncthreads();
  }
}

// ---------------------------------------------------------------------------
// K2: normalized prototype slots scaled by 1/sqrt(T); wave-per-slot (4 slots
// concurrent, float4 loads, shfl_xor reduce) -- R8's serial 17-slot loop was
// ~14us of latency.  Emits exact bf16 hi/lo planes; valid/cnt/wcol/cnt_exist.
// grid K_ blocks x 256 thr.
// ---------------------------------------------------------------------------
__global__ __launch_bounds__(256) void k_protos(
    const float* __restrict__ psum, const unsigned* __restrict__ counts,
    const float* __restrict__ prototypes, unsigned short* __restrict__ PmH,
    unsigned short* __restrict__ PmL, int* __restrict__ valid,
    float* __restrict__ wcol, float* __restrict__ cntk,
    float* __restrict__ scal) {
  const int k = blockIdx.x;
  const int tid = threadIdx.x, wv = tid >> 6, ln = tid & 63;
  __shared__ int s_valid[S_];
  for (int s = wv; s < S_; s += 4) {
    float val[4];
    int pres;
    if (s < B_) {
      const unsigned cb = counts[s * K_ + k];
      float4 v = {0.f, 0.f, 0.f, 0.f};
#pragma unroll
      for (int pq = 0; pq < NPQ_; ++pq) {
        const float4 t4 =
            *(const float4*)&psum[((size_t)(pq * 16 + s) * K_ + k) * 256 + ln * 4];
        v.x += t4.x; v.y += t4.y; v.z += t4.z; v.w += t4.w;
      }
      const float cbf = fmaxf((float)cb, 1.f);
      val[0] = v.x / cbf; val[1] = v.y / cbf; val[2] = v.z / cbf; val[3] = v.w / cbf;
      pres = (cb > 0u) && (k >= 1);
    } else {
      const float4 pv4 = *(const float4*)&prototypes[k * C_ + ln * 4];
      val[0] = pv4.x; val[1] = pv4.y; val[2] = pv4.z; val[3] = pv4.w;
      pres = (k >= 1);
    }
    float ss = val[0] * val[0] + val[1] * val[1] + val[2] * val[2] + val[3] * val[3];
#pragma unroll
    for (int m = 1; m < 64; m <<= 1) ss += __shfl_xor(ss, m);
    const float nrm = fmaxf(sqrtf(ss), 1e-12f);
    unsigned short h[4], l[4];
#pragma unroll
    for (int j = 0; j < 4; ++j) {
      const float pv = pres ? (val[j] / nrm) * INV_SQRT_T : 0.f;
      const unsigned u = __float_as_uint(pv);
      const float lo = pv - __uint_as_float(u & 0xFFFF0000u);
      h[j] = (unsigned short)(u >> 16);
      l[j] = (unsigned short)(__float_as_uint(lo) >> 16);
    }
    const size_t idx = ((size_t)k * S_ + s) * C_ + ln * 4;
    *(ushort4*)&PmH[idx] = make_ushort4(h[0], h[1], h[2], h[3]);
    *(ushort4*)&PmL[idx] = make_ushort4(l[0], l[1], l[2], l[3]);
    if (ln == 0) s_valid[s] = pres;
  }
  __syncthreads();
  if (tid == 0) {
    int cnt = 0;
    for (int s = 0; s < S_; ++s) cnt += s_valid[s];
    const float cf = (float)cnt;
    cntk[k] = cf;
    const float wvv = 1.f / fmaxf(cf, 1.f);
    for (int s = 0; s < S_; ++s) {
      valid[k * S_ + s] = s_valid[s];
      wcol[k * S_ + s] = s_valid[s] ? wvv : 0.f;
    }
    if (cnt > 1 && k >= 1) atomAddGlb(&scal[1], 1.f);
  }
}

// ---------------------------------------------------------------------------
// K3: Gram G = Pm*Pm^T via bf16 MFMA with exact hi/lo split:
// G ~= H*H^T + H*L^T + L*H^T   (lo*lo ~ 2^-16 relative, dropped).
// 64x64 tile per wave, 4 waves/block, grid 196 blocks = 784 tiles.
// ---------------------------------------------------------------------------
__global__ __launch_bounds__(256) void k_gram(
    const unsigned short* __restrict__ PmH,
    const unsigned short* __restrict__ PmL, float* __restrict__ G) {
  const int tid = threadIdx.x;
  const int wv = tid >> 6, ln = tid & 63;
  const int gid = blockIdx.x * 4 + wv;       // 0..783
  const int ri = gid / 28, cj = gid % 28;    // 64x64 tile coords
  const int lg = ln >> 4, lc = ln & 15;

  f32x4 acc[4][4];
#pragma unroll
  for (int m = 0; m < 4; ++m)
#pragma unroll
    for (int n = 0; n < 4; ++n) acc[m][n] = (f32x4)0.f;

#pragma unroll
  for (int ks = 0; ks < 8; ++ks) {
    const int kb = ks * 32 + lg * 8;
    bf16x8 aH[4], aL[4], bH[4], bL[4];
#pragma unroll
    for (int m = 0; m < 4; ++m) {
      const size_t ra = (size_t)(ri * 64 + m * 16 + lc) * C_ + kb;
      aH[m] = __builtin_bit_cast(bf16x8, *(const i32x4*)&PmH[ra]);
      aL[m] = __builtin_bit_cast(bf16x8, *(const i32x4*)&PmL[ra]);
      const size_t rb = (size_t)(cj * 64 + m * 16 + lc) * C_ + kb;
      bH[m] = __builtin_bit_cast(bf16x8, *(const i32x4*)&PmH[rb]);
      bL[m] = __builtin_bit_cast(bf16x8, *(const i32x4*)&PmL[rb]);
    }
#pragma unroll
    for (int m = 0; m < 4; ++m)
#pragma unroll
      for (int n = 0; n < 4; ++n) {
        acc[m][n] = __builtin_amdgcn_mfma_f32_16x16x32_bf16(aH[m], bH[n], acc[m][n], 0, 0, 0);
        acc[m][n] = __builtin_amdgcn_mfma_f32_16x16x32_bf16(aH[m], bL[n], acc[m][n], 0, 0, 0);
        acc[m][n] = __builtin_amdgcn_mfma_f32_16x16x32_bf16(aL[m], bH[n], acc[m][n], 0, 0, 0);
      }
  }
  // D: row = m*16 + lg*4 + r, col = n*16 + lc
#pragma unroll
  for (int m = 0; m < 4; ++m)
#pragma unroll
    for (int r = 0; r < 4; ++r) {
      float* gr = &G[(size_t)(ri * 64 + m * 16 + lg * 4 + r) * GN_ + cj * 64 + lc];
#pragma unroll
      for (int n = 0; n < 4; ++n) gr[n * 16] = acc[m][n][r];
    }
}

// ---------------------------------------------------------------------------
// K4: per-anchor loss. grid (16 slots, 101 classes), block 256.
// ---------------------------------------------------------------------------
__global__ __launch_bounds__(256) void k_loss(
    const float* __restrict__ G, const int* __restrict__ valid,
    const float* __restrict__ wcol, const float* __restrict__ cntk,
    float* __restrict__ scal) {
  const int s = blockIdx.x;  // 0..15 (batch slots only = anchors)
  const int k = blockIdx.y;  // 0..100
  const int a = k * S_ + s;
  if (!valid[a]) return;  // uniform over block
  const int tid = threadIdx.x;
  const float* row = G + (size_t)a * GN_;
  float dpart = 0.f;
  for (int j = tid; j < GN_; j += 256) dpart += wcol[j] * __expf(row[j]);
  __shared__ float red[4];
#pragma unroll
  for (int o = 32; o > 0; o >>= 1) dpart += __shfl_down(dpart, o);
  if ((tid & 63) == 0) red[tid >> 6] = dpart;
  __syncthreads();
  if (tid == 0) {
    const float den = red[0] + red[1] + red[2] + red[3];
    float pos = 0.f;
    for (int n = 0; n < S_; ++n)
      if (valid[k * S_ + n]) pos += row[k * S_ + n];
    pos -= row[a];  // remove self term (diag)
    const float np = cntk[k] - 1.f;
    const float npc = fmaxf(np, 1.f);
    const float pa = -(pos - np * logf(den)) / (npc * npc);
    atomAddGlb(&scal[0], pa);
  }
}

__global__ void k_final(const float* __restrict__ scal, float* __restrict__ out) {
  out[0] = 0.1f * scal[0] / scal[1];
}

// ---------------------------------------------------------------------------
extern "C" void kernel_launch(void* const* d_in, const int* in_sizes, int n_in,
                              void* d_out, int out_size, void* d_ws, size_t ws_size,
                              hipStream_t stream) {
  const int* labels = (const int*)d_in[0];
  const float* feats = (const float*)d_in[1];
  const float* protos = (const float*)d_in[2];
  float* out = (float*)d_out;

  char* wsb = (char*)d_ws;
  size_t o = 0;
  auto nxt = [&](size_t bytes) {
    size_t r = o;
    o = (o + bytes + 255) & ~(size_t)255;
    return r;
  };
  // Small region (memset each call):
  const size_t off_cnts = nxt((size_t)B_ * K_ * 4);
  const size_t off_PH   = nxt((size_t)GN_ * C_ * 2);
  const size_t off_PL   = nxt((size_t)GN_ * C_ * 2);
  const size_t off_val  = nxt((size_t)GN_ * 4);
  const size_t off_w    = nxt((size_t)GN_ * 4);
  const size_t off_cntk = nxt((size_t)K_ * 4);
  const size_t off_scal = nxt(8);
  const size_t small_end = o;
  // Big region: psum partials and G share storage (disjoint lifetimes).
  const size_t psum_bytes = (size_t)NPQ_ * 16 * K_ * 256 * 4;  // 13.2 MB
  const size_t g_bytes = (size_t)GN_ * GN_ * 4;                // 12.8 MB
  const size_t off_big = nxt(psum_bytes > g_bytes ? psum_bytes : g_bytes);

  unsigned* w_cnts = (unsigned*)(wsb + off_cnts);
  unsigned short* w_PH = (unsigned short*)(wsb + off_PH);
  unsigned short* w_PL = (unsigned short*)(wsb + off_PL);
  int* w_valid     = (int*)(wsb + off_val);
  float* w_w       = (float*)(wsb + off_w);
  float* w_cntk    = (float*)(wsb + off_cntk);
  float* w_scal    = (float*)(wsb + off_scal);
  float* w_psum    = (float*)(wsb + off_big);
  float* w_G       = (float*)(wsb + off_big);

  // Zero the small region (PmH/PmL pad rows feed k_gram; scalars accumulate).
  hipMemsetAsync(d_ws, 0, small_end, stream);

  k_segsum<<<1040, 256, 0, stream>>>(labels, feats, w_psum, w_cnts);
  k_protos<<<K_, 256, 0, stream>>>(w_psum, w_cnts, protos, w_PH, w_PL, w_valid,
                                   w_w, w_cntk, w_scal);
  k_gram<<<196, 256, 0, stream>>>(w_PH, w_PL, w_G);
  k_loss<<<dim3(B_, K_), 256, 0, stream>>>(w_G, w_valid, w_w, w_cntk, w_scal);
  k_final<<<1, 1, 0, stream>>>(w_scal, out);
}

// Round 10
// 131.987 us; speedup vs baseline: 1.2128x; 1.2128x over previous
//
#include <hip/hip_runtime.h>
#include <hip/hip_bf16.h>
#include <math.h>

// Problem constants (fixed by setup_inputs)
#define B_    16
#define C_    256
#define P_    16384          // 128*128
#define K_    101            // num_class + 1
#define S_    17             // B + 1 slots per class
#define V_    1717           // K_ * S_
#define GN_   1792           // V_ padded to 28*64
#define NPQ_  8              // pixel-slice partials (2048 px per slice)
#define TEMP_ 0.07f
#define INV_SQRT_T 3.7796447300922720f   // 1/sqrt(0.07)

typedef __bf16 bf16x8 __attribute__((ext_vector_type(8)));
typedef float f32x4 __attribute__((ext_vector_type(4)));
typedef int   i32x4 __attribute__((ext_vector_type(4)));

__device__ __forceinline__ void atomAddGlb(float* p, float v) {
  __hip_atomic_fetch_add(p, v, __ATOMIC_RELAXED, __HIP_MEMORY_SCOPE_AGENT);
}

// pack fp32 x into one dword: low16 = bf16(hi), high16 = bf16(x - hi). Exact.
__device__ __forceinline__ unsigned packHiLo(float x) {
  const unsigned u = __float_as_uint(x);
  const unsigned h = u & 0xFFFF0000u;
  const unsigned l = __float_as_uint(x - __uint_as_float(h));
  return __builtin_amdgcn_perm(l, u, 0x07060302u);  // [l3,l2,u3,u2]
}

// ---------------------------------------------------------------------------
// K1: segmented sums via MFMA -- R8 structure (barrier-free direct loads; the
// R9 LDS-staged variant regressed: barrier-phased waves expose load latency).
// Change vs R8: 16 channels/wave (acc 28 VGPR, peak live ~58) so
// __launch_bounds__(256,8) holds VGPR<=64 -> 8 waves/SIMD (was 4); 2048
// working blocks (b 16 x pqg 8 x cg 16) = 8192 waves = exactly 8/SIMD.
// Interleaved hi|lo k-packing: pixel p -> k-slots (2p,2p+1), A duplicates the
// onehot across the pair (0x3F803F80).  Same verified k-slot<->pixel map.
// Blocks 2048..2063: per-batch label histogram.
// ---------------------------------------------------------------------------
__global__ __launch_bounds__(256, 8) void k_segsum(
    const int* __restrict__ labels, const float* __restrict__ feats,
    float* __restrict__ psum, unsigned* __restrict__ counts) {
  __shared__ unsigned s_cnt[102];
  __shared__ f32x4 s_red[256];
  const int id = blockIdx.x;
  const int tid = threadIdx.x;

  if (id >= 2048) {  // ---- label counts for batch id-2048 ----
    const int b = id - 2048;
    if (tid < 102) s_cnt[tid] = 0u;
    __syncthreads();
    for (int i = 0; i < 64; ++i) {
      int lab = labels[b * P_ + i * 256 + tid];
      if ((unsigned)lab > 100u) lab = 101;
      atomicAdd(&s_cnt[lab], 1u);
    }
    __syncthreads();
    if (tid < K_) counts[b * K_ + tid] = s_cnt[tid];
    return;
  }

  // cg innermost so the 16 blocks sharing (b,pqg) labels are dispatch-adjacent
  const int cg = id & 15, pqg = (id >> 4) & 7, b = id >> 7;
  const int wv = tid >> 6, ln = tid & 63;
  const int lg = ln >> 4;    // lane group 0..3
  const int lc = ln & 15;    // A row (class) / B col (channel)
  const int pbase = pqg * 2048 + wv * 512;
  const int* lptr = labels + b * P_ + pbase + lg * 4;
  const float* frow =
      feats + ((size_t)b * C_ + cg * 16 + lc) * P_ + pbase + lg * 4;

  f32x4 acc[7];
#pragma unroll
  for (int t = 0; t < 7; ++t) acc[t] = (f32x4)0.f;

  for (int w = 0; w < 16; ++w) {
    const int off = w * 32;
    // labels for window0 (px lg*4..+3) and window1 (px 16+lg*4..+3)
    const i32x4 la0 = *(const i32x4*)&lptr[off];
    const i32x4 la1 = *(const i32x4*)&lptr[off + 16];
    const float4 f0 = *(const float4*)&frow[off];
    const float4 f1 = *(const float4*)&frow[off + 16];
    i32x4 p0, p1;
    p0[0] = (int)packHiLo(f0.x); p0[1] = (int)packHiLo(f0.y);
    p0[2] = (int)packHiLo(f0.z); p0[3] = (int)packHiLo(f0.w);
    p1[0] = (int)packHiLo(f1.x); p1[1] = (int)packHiLo(f1.y);
    p1[2] = (int)packHiLo(f1.z); p1[3] = (int)packHiLo(f1.w);
    const bf16x8 b0 = __builtin_bit_cast(bf16x8, p0);
    const bf16x8 b1 = __builtin_bit_cast(bf16x8, p1);
    int d0[4], d1[4];
#pragma unroll
    for (int r = 0; r < 4; ++r) { d0[r] = la0[r] - lc; d1[r] = la1[r] - lc; }
#pragma unroll
    for (int t = 0; t < 7; ++t) {
      const int m0 = t * 16;
      i32x4 a0v, a1v;
#pragma unroll
      for (int r = 0; r < 4; ++r) {
        a0v[r] = (d0[r] == m0) ? (int)0x3F803F80 : 0;
        a1v[r] = (d1[r] == m0) ? (int)0x3F803F80 : 0;
      }
      acc[t] = __builtin_amdgcn_mfma_f32_16x16x32_bf16(
          __builtin_bit_cast(bf16x8, a0v), b0, acc[t], 0, 0, 0);
      acc[t] = __builtin_amdgcn_mfma_f32_16x16x32_bf16(
          __builtin_bit_cast(bf16x8, a1v), b1, acc[t], 0, 0, 0);
    }
  }
  // ---- block reduce over the 4 waves; wave 0 writes the psum slab ----
  float* pbas = psum + ((size_t)(pqg * 16 + b) * K_) * 256 + cg * 16 + lc;
#pragma unroll
  for (int t = 0; t < 7; ++t) {
    s_red[wv * 64 + ln] = acc[t];
    __syncthreads();
    if (wv == 0) {
      const f32x4 a0 = s_red[ln], a1 = s_red[64 + ln];
      const f32x4 a2 = s_red[128 + ln], a3 = s_red[192 + ln];
#pragma unroll
      for (int r = 0; r < 4; ++r) {
        const int row = t * 16 + lg * 4 + r;
        if (row < K_)
          pbas[(size_t)row * 256] = a0[r] + a1[r] + a2[r] + a3[r];
      }
    }
    __syncthreads();
  }
}

// ---------------------------------------------------------------------------
// K2: normalized prototype slots scaled by 1/sqrt(T); wave-per-slot (4 slots
// concurrent, float4 loads, shfl_xor reduce).  Emits exact bf16 hi/lo planes;
// valid/cnt/wcol/cnt_exist.  grid K_ blocks x 256 thr.
// ---------------------------------------------------------------------------
__global__ __launch_bounds__(256) void k_protos(
    const float* __restrict__ psum, const unsigned* __restrict__ counts,
    const float* __restrict__ prototypes, unsigned short* __restrict__ PmH,
    unsigned short* __restrict__ PmL, int* __restrict__ valid,
    float* __restrict__ wcol, float* __restrict__ cntk,
    float* __restrict__ scal) {
  const int k = blockIdx.x;
  const int tid = threadIdx.x, wv = tid >> 6, ln = tid & 63;
  __shared__ int s_valid[S_];
  for (int s = wv; s < S_; s += 4) {
    float val[4];
    int pres;
    if (s < B_) {
      const unsigned cb = counts[s * K_ + k];
      float4 v = {0.f, 0.f, 0.f, 0.f};
#pragma unroll
      for (int pq = 0; pq < NPQ_; ++pq) {
        const float4 t4 =
            *(const float4*)&psum[((size_t)(pq * 16 + s) * K_ + k) * 256 + ln * 4];
        v.x += t4.x; v.y += t4.y; v.z += t4.z; v.w += t4.w;
      }
      const float cbf = fmaxf((float)cb, 1.f);
      val[0] = v.x / cbf; val[1] = v.y / cbf; val[2] = v.z / cbf; val[3] = v.w / cbf;
      pres = (cb > 0u) && (k >= 1);
    } else {
      const float4 pv4 = *(const float4*)&prototypes[k * C_ + ln * 4];
      val[0] = pv4.x; val[1] = pv4.y; val[2] = pv4.z; val[3] = pv4.w;
      pres = (k >= 1);
    }
    float ss = val[0] * val[0] + val[1] * val[1] + val[2] * val[2] + val[3] * val[3];
#pragma unroll
    for (int m = 1; m < 64; m <<= 1) ss += __shfl_xor(ss, m);
    const float nrm = fmaxf(sqrtf(ss), 1e-12f);
    unsigned short h[4], l[4];
#pragma unroll
    for (int j = 0; j < 4; ++j) {
      const float pv = pres ? (val[j] / nrm) * INV_SQRT_T : 0.f;
      const unsigned u = __float_as_uint(pv);
      const float lo = pv - __uint_as_float(u & 0xFFFF0000u);
      h[j] = (unsigned short)(u >> 16);
      l[j] = (unsigned short)(__float_as_uint(lo) >> 16);
    }
    const size_t idx = ((size_t)k * S_ + s) * C_ + ln * 4;
    *(ushort4*)&PmH[idx] = make_ushort4(h[0], h[1], h[2], h[3]);
    *(ushort4*)&PmL[idx] = make_ushort4(l[0], l[1], l[2], l[3]);
    if (ln == 0) s_valid[s] = pres;
  }
  __syncthreads();
  if (tid == 0) {
    int cnt = 0;
    for (int s = 0; s < S_; ++s) cnt += s_valid[s];
    const float cf = (float)cnt;
    cntk[k] = cf;
    const float wvv = 1.f / fmaxf(cf, 1.f);
    for (int s = 0; s < S_; ++s) {
      valid[k * S_ + s] = s_valid[s];
      wcol[k * S_ + s] = s_valid[s] ? wvv : 0.f;
    }
    if (cnt > 1 && k >= 1) atomAddGlb(&scal[1], 1.f);
  }
}

// ---------------------------------------------------------------------------
// K3: Gram G = Pm*Pm^T via bf16 MFMA with exact hi/lo split:
// G ~= H*H^T + H*L^T + L*H^T   (lo*lo ~ 2^-16 relative, dropped).
// 64x64 tile per wave, 4 waves/block, grid 196 blocks = 784 tiles.
// ---------------------------------------------------------------------------
__global__ __launch_bounds__(256) void k_gram(
    const unsigned short* __restrict__ PmH,
    const unsigned short* __restrict__ PmL, float* __restrict__ G) {
  const int tid = threadIdx.x;
  const int wv = tid >> 6, ln = tid & 63;
  const int gid = blockIdx.x * 4 + wv;       // 0..783
  const int ri = gid / 28, cj = gid % 28;    // 64x64 tile coords
  const int lg = ln >> 4, lc = ln & 15;

  f32x4 acc[4][4];
#pragma unroll
  for (int m = 0; m < 4; ++m)
#pragma unroll
    for (int n = 0; n < 4; ++n) acc[m][n] = (f32x4)0.f;

#pragma unroll
  for (int ks = 0; ks < 8; ++ks) {
    const int kb = ks * 32 + lg * 8;
    bf16x8 aH[4], aL[4], bH[4], bL[4];
#pragma unroll
    for (int m = 0; m < 4; ++m) {
      const size_t ra = (size_t)(ri * 64 + m * 16 + lc) * C_ + kb;
      aH[m] = __builtin_bit_cast(bf16x8, *(const i32x4*)&PmH[ra]);
      aL[m] = __builtin_bit_cast(bf16x8, *(const i32x4*)&PmL[ra]);
      const size_t rb = (size_t)(cj * 64 + m * 16 + lc) * C_ + kb;
      bH[m] = __builtin_bit_cast(bf16x8, *(const i32x4*)&PmH[rb]);
      bL[m] = __builtin_bit_cast(bf16x8, *(const i32x4*)&PmL[rb]);
    }
#pragma unroll
    for (int m = 0; m < 4; ++m)
#pragma unroll
      for (int n = 0; n < 4; ++n) {
        acc[m][n] = __builtin_amdgcn_mfma_f32_16x16x32_bf16(aH[m], bH[n], acc[m][n], 0, 0, 0);
        acc[m][n] = __builtin_amdgcn_mfma_f32_16x16x32_bf16(aH[m], bL[n], acc[m][n], 0, 0, 0);
        acc[m][n] = __builtin_amdgcn_mfma_f32_16x16x32_bf16(aL[m], bH[n], acc[m][n], 0, 0, 0);
      }
  }
  // D: row = m*16 + lg*4 + r, col = n*16 + lc
#pragma unroll
  for (int m = 0; m < 4; ++m)
#pragma unroll
    for (int r = 0; r < 4; ++r) {
      float* gr = &G[(size_t)(ri * 64 + m * 16 + lg * 4 + r) * GN_ + cj * 64 + lc];
#pragma unroll
      for (int n = 0; n < 4; ++n) gr[n * 16] = acc[m][n][r];
    }
}

// ---------------------------------------------------------------------------
// K4: per-anchor loss. grid (16 slots, 101 classes), block 256.
// ---------------------------------------------------------------------------
__global__ __launch_bounds__(256) void k_loss(
    const float* __restrict__ G, const int* __restrict__ valid,
    const float* __restrict__ wcol, const float* __restrict__ cntk,
    float* __restrict__ scal) {
  const int s = blockIdx.x;  // 0..15 (batch slots only = anchors)
  const int k = blockIdx.y;  // 0..100
  const int a = k * S_ + s;
  if (!valid[a]) return;  // uniform over block
  const int tid = threadIdx.x;
  const float* row = G + (size_t)a * GN_;
  float dpart = 0.f;
  for (int j = tid; j < GN_; j += 256) dpart += wcol[j] * __expf(row[j]);
  __shared__ float red[4];
#pragma unroll
  for (int o = 32; o > 0; o >>= 1) dpart += __shfl_down(dpart, o);
  if ((tid & 63) == 0) red[tid >> 6] = dpart;
  __syncthreads();
  if (tid == 0) {
    const float den = red[0] + red[1] + red[2] + red[3];
    float pos = 0.f;
    for (int n = 0; n < S_; ++n)
      if (valid[k * S_ + n]) pos += row[k * S_ + n];
    pos -= row[a];  // remove self term (diag)
    const float np = cntk[k] - 1.f;
    const float npc = fmaxf(np, 1.f);
    const float pa = -(pos - np * logf(den)) / (npc * npc);
    atomAddGlb(&scal[0], pa);
  }
}

__global__ void k_final(const float* __restrict__ scal, float* __restrict__ out) {
  out[0] = 0.1f * scal[0] / scal[1];
}

// ---------------------------------------------------------------------------
extern "C" void kernel_launch(void* const* d_in, const int* in_sizes, int n_in,
                              void* d_out, int out_size, void* d_ws, size_t ws_size,
                              hipStream_t stream) {
  const int* labels = (const int*)d_in[0];
  const float* feats = (const float*)d_in[1];
  const float* protos = (const float*)d_in[2];
  float* out = (float*)d_out;

  char* wsb = (char*)d_ws;
  size_t o = 0;
  auto nxt = [&](size_t bytes) {
    size_t r = o;
    o = (o + bytes + 255) & ~(size_t)255;
    return r;
  };
  // Small region (memset each call):
  const size_t off_cnts = nxt((size_t)B_ * K_ * 4);
  const size_t off_PH   = nxt((size_t)GN_ * C_ * 2);
  const size_t off_PL   = nxt((size_t)GN_ * C_ * 2);
  const size_t off_val  = nxt((size_t)GN_ * 4);
  const size_t off_w    = nxt((size_t)GN_ * 4);
  const size_t off_cntk = nxt((size_t)K_ * 4);
  const size_t off_scal = nxt(8);
  const size_t small_end = o;
  // Big region: psum partials and G share storage (disjoint lifetimes).
  const size_t psum_bytes = (size_t)NPQ_ * 16 * K_ * 256 * 4;  // 13.2 MB
  const size_t g_bytes = (size_t)GN_ * GN_ * 4;                // 12.8 MB
  const size_t off_big = nxt(psum_bytes > g_bytes ? psum_bytes : g_bytes);

  unsigned* w_cnts = (unsigned*)(wsb + off_cnts);
  unsigned short* w_PH = (unsigned short*)(wsb + off_PH);
  unsigned short* w_PL = (unsigned short*)(wsb + off_PL);
  int* w_valid     = (int*)(wsb + off_val);
  float* w_w       = (float*)(wsb + off_w);
  float* w_cntk    = (float*)(wsb + off_cntk);
  float* w_scal    = (float*)(wsb + off_scal);
  float* w_psum    = (float*)(wsb + off_big);
  float* w_G       = (float*)(wsb + off_big);

  // Zero the small region (PmH/PmL pad rows feed k_gram; scalars accumulate).
  hipMemsetAsync(d_ws, 0, small_end, stream);

  k_segsum<<<2064, 256, 0, stream>>>(labels, feats, w_psum, w_cnts);
  k_protos<<<K_, 256, 0, stream>>>(w_psum, w_cnts, protos, w_PH, w_PL, w_valid,
                                   w_w, w_cntk, w_scal);
  k_gram<<<196, 256, 0, stream>>>(w_PH, w_PL, w_G);
  k_loss<<<dim3(B_, K_), 256, 0, stream>>>(w_G, w_valid, w_w, w_cntk, w_scal);
  k_final<<<1, 1, 0, stream>>>(w_scal, out);
}